// Round 1
// baseline (1135.540 us; speedup 1.0000x reference)
//
#include <hip/hip_runtime.h>
#include <hip/hip_fp16.h>

// MoE: B=4 S=2048 D=1024 E=8 K=2 H=4096. T=8192 tokens, 16384 assignments.
// Sparse grouped-GEMM MoE in fp16 MFMA (fp32 accum). ws required ~338MB.

#define T_TOK 8192
#define D_IN  1024
#define E_EXP 8
#define H_HID 4096
#define NSLOT (T_TOK * 2)        // total assignments (always exactly 2 per token)
#define NSLOT_PAD (NSLOT + 128)  // pad so partial last tile stays in-bounds

typedef _Float16 f16;
typedef __attribute__((ext_vector_type(8))) _Float16 f16x8;
typedef __attribute__((ext_vector_type(4))) _Float16 f16x4;
typedef __attribute__((ext_vector_type(4))) float f32x4;

__device__ __forceinline__ void gload_lds16(const void* g, void* l) {
  __builtin_amdgcn_global_load_lds(
      (const __attribute__((address_space(1))) unsigned int*)g,
      (__attribute__((address_space(3))) unsigned int*)l, 16, 0, 0);
}

// ---------------- conversion kernels ----------------

__global__ __launch_bounds__(256) void convert_x_kernel(
    const float* __restrict__ x, f16* __restrict__ xb, int n4) {
  int i = blockIdx.x * 256 + threadIdx.x;
  if (i >= n4) return;
  float4 v = ((const float4*)x)[i];
  f16x4 o = {(f16)v.x, (f16)v.y, (f16)v.z, (f16)v.w};
  *(f16x4*)(xb + (size_t)i * 4) = o;
}

// src [batch][R][C] f32  ->  dst [batch][C][R] f16  (transpose + convert)
__global__ __launch_bounds__(256) void transpose_cvt_kernel(
    const float* __restrict__ src, f16* __restrict__ dst, int R, int C) {
  __shared__ float tile[32][33];
  int b = blockIdx.z;
  const float* s = src + (size_t)b * R * C;
  f16* d = dst + (size_t)b * R * C;
  int c0 = blockIdx.x * 32, r0 = blockIdx.y * 32;
  int tr = threadIdx.x >> 3;          // 0..31
  int tc4 = (threadIdx.x & 7) * 4;    // 0,4,..,28
  float4 v = *(const float4*)(s + (size_t)(r0 + tr) * C + c0 + tc4);
  tile[tr][tc4 + 0] = v.x;
  tile[tr][tc4 + 1] = v.y;
  tile[tr][tc4 + 2] = v.z;
  tile[tr][tc4 + 3] = v.w;
  __syncthreads();
  f16x4 o = {(f16)tile[tc4 + 0][tr], (f16)tile[tc4 + 1][tr],
             (f16)tile[tc4 + 2][tr], (f16)tile[tc4 + 3][tr]};
  *(f16x4*)(d + (size_t)(c0 + tr) * R + r0 + tc4) = o;
}

// ---------------- router ----------------

__global__ __launch_bounds__(256) void router_kernel(
    const float* __restrict__ x, const float* __restrict__ Wr,
    const float* __restrict__ br, int* __restrict__ eidx,
    float2* __restrict__ pval, int* __restrict__ counts) {
  int lane = threadIdx.x & 63, wid = threadIdx.x >> 6;
  int t = blockIdx.x * 4 + wid;
  const float* xr = x + (size_t)t * D_IN;
  float s[8] = {0.f, 0.f, 0.f, 0.f, 0.f, 0.f, 0.f, 0.f};
  int dbase = lane * 16;
#pragma unroll
  for (int i = 0; i < 4; ++i) {
    float4 xv = *(const float4*)(xr + dbase + i * 4);
    const float xs[4] = {xv.x, xv.y, xv.z, xv.w};
#pragma unroll
    for (int j = 0; j < 4; ++j) {
      const float* wr = Wr + (size_t)(dbase + i * 4 + j) * E_EXP;
      float4 w0 = *(const float4*)wr;
      float4 w1 = *(const float4*)(wr + 4);
      float xvj = xs[j];
      s[0] += xvj * w0.x; s[1] += xvj * w0.y; s[2] += xvj * w0.z; s[3] += xvj * w0.w;
      s[4] += xvj * w1.x; s[5] += xvj * w1.y; s[6] += xvj * w1.z; s[7] += xvj * w1.w;
    }
  }
#pragma unroll
  for (int off = 32; off; off >>= 1)
#pragma unroll
    for (int e = 0; e < 8; ++e) s[e] += __shfl_xor(s[e], off);
  if (lane == 0) {
    float v[8];
#pragma unroll
    for (int e = 0; e < 8; ++e) v[e] = s[e] + br[e];
    int i0 = 0; float v0 = v[0];
#pragma unroll
    for (int e = 1; e < 8; ++e) if (v[e] > v0) { v0 = v[e]; i0 = e; }
    int i1 = -1; float v1 = -1e30f;
#pragma unroll
    for (int e = 0; e < 8; ++e)
      if (e != i0 && v[e] > v1) { v1 = v[e]; i1 = e; }
    float ed = __expf(v1 - v0);          // <= 1
    float inv = 1.f / (1.f + ed);
    eidx[t] = i0 | (i1 << 8);
    pval[t] = make_float2(inv, ed * inv);
    atomicAdd(&counts[i0], 1);
    atomicAdd(&counts[i1], 1);
  }
}

__global__ void scan_kernel(const int* __restrict__ counts, int* __restrict__ offsets) {
  if (threadIdx.x == 0) {
    int acc = 0;
#pragma unroll
    for (int e = 0; e < E_EXP; ++e) { offsets[e] = acc; acc += counts[e]; }
    offsets[E_EXP] = acc;
  }
}

__global__ __launch_bounds__(256) void scatter_kernel(
    const int* __restrict__ eidx, const float2* __restrict__ pval,
    const int* __restrict__ offsets, int* __restrict__ cursors,
    int* __restrict__ perm, float* __restrict__ gatew) {
  int t = blockIdx.x * 256 + threadIdx.x;
  if (t >= T_TOK) return;
  int ei = eidx[t];
  float2 p = pval[t];
  int e0 = ei & 0xff, e1 = (ei >> 8) & 0xff;
  int s0 = offsets[e0] + atomicAdd(&cursors[e0], 1);
  perm[s0] = t; gatew[s0] = p.x;
  int s1 = offsets[e1] + atomicAdd(&cursors[e1], 1);
  perm[s1] = t; gatew[s1] = p.y;
}

// ---------------- FFN1: h = silu(X Wg + bg) * (X Wu + bu) ----------------
// tile: 128 slots x 64 H-cols, both projections. 4 waves, each 32x64 of both.
__global__ __launch_bounds__(256) void ffn1_kernel(
    const f16* __restrict__ xb, const f16* __restrict__ wgt,
    const f16* __restrict__ wut, const float* __restrict__ bg,
    const float* __restrict__ bu, const int* __restrict__ offsets,
    const int* __restrict__ perm, f16* __restrict__ hbuf) {
  __shared__ f16 aT[128 * 32];
  __shared__ f16 bgT[64 * 32];
  __shared__ f16 buT[64 * 32];
  int e = blockIdx.z;
  int off = offsets[e];
  int cnt = offsets[e + 1] - off;
  int mt = blockIdx.y;
  if (mt * 128 >= cnt) return;
  int n0 = blockIdx.x * 64;
  int tid = threadIdx.x, lane = tid & 63, wid = tid >> 6;

  // A staging source pointers (gathered token rows), 2 issues of 256x16B
  const f16* ga[2];
#pragma unroll
  for (int i = 0; i < 2; ++i) {
    int linear = i * 256 + tid;
    int row = linear >> 2, chunk = linear & 3;
    int slot = off + mt * 128 + row;
    int srow = min(slot, off + cnt - 1);
    int token = perm[srow];
    ga[i] = xb + (size_t)token * D_IN + chunk * 8;
  }
  const f16* gbg = wgt + (size_t)e * H_HID * D_IN + (size_t)(n0 + (tid >> 2)) * D_IN + (tid & 3) * 8;
  const f16* gbu = wut + (size_t)e * H_HID * D_IN + (size_t)(n0 + (tid >> 2)) * D_IN + (tid & 3) * 8;

  f32x4 accg[2][4] = {};
  f32x4 accu[2][4] = {};

  for (int kt = 0; kt < D_IN / 32; ++kt) {
    __syncthreads();
#pragma unroll
    for (int i = 0; i < 2; ++i)
      gload_lds16(ga[i] + kt * 32, &aT[(i * 256 + wid * 64) * 8]);
    gload_lds16(gbg + kt * 32, &bgT[(wid * 64) * 8]);
    gload_lds16(gbu + kt * 32, &buT[(wid * 64) * 8]);
    __syncthreads();
    f16x8 af[2], bgf[4], buf_[4];
    int krow = (lane >> 4) * 8;
#pragma unroll
    for (int m = 0; m < 2; ++m)
      af[m] = *(const f16x8*)&aT[(wid * 32 + m * 16 + (lane & 15)) * 32 + krow];
#pragma unroll
    for (int n = 0; n < 4; ++n) {
      bgf[n] = *(const f16x8*)&bgT[(n * 16 + (lane & 15)) * 32 + krow];
      buf_[n] = *(const f16x8*)&buT[(n * 16 + (lane & 15)) * 32 + krow];
    }
#pragma unroll
    for (int m = 0; m < 2; ++m)
#pragma unroll
      for (int n = 0; n < 4; ++n) {
        accg[m][n] = __builtin_amdgcn_mfma_f32_16x16x32_f16(af[m], bgf[n], accg[m][n], 0, 0, 0);
        accu[m][n] = __builtin_amdgcn_mfma_f32_16x16x32_f16(af[m], buf_[n], accu[m][n], 0, 0, 0);
      }
  }

#pragma unroll
  for (int n = 0; n < 4; ++n) {
    int h = n0 + n * 16 + (lane & 15);
    float bgv = bg[e * H_HID + h];
    float buv = bu[e * H_HID + h];
#pragma unroll
    for (int m = 0; m < 2; ++m) {
#pragma unroll
      for (int r = 0; r < 4; ++r) {
        int row = wid * 32 + m * 16 + (lane >> 4) * 4 + r;
        int local = mt * 128 + row;
        if (local < cnt) {
          float g = accg[m][n][r] + bgv;
          float u = accu[m][n][r] + buv;
          float hv = (g / (1.f + __expf(-g))) * u;  // silu(g)*u
          hbuf[(size_t)(off + local) * H_HID + h] = (f16)hv;
        }
      }
    }
  }
}

// ---------------- FFN2: out += gate * (h Wd + bd) ----------------
// m97 shape: 128x128 tile, BK=32, 4 waves 2x2 each 64x64
__global__ __launch_bounds__(256) void ffn2_kernel(
    const f16* __restrict__ hbuf, const f16* __restrict__ wdt,
    const float* __restrict__ bd, const int* __restrict__ offsets,
    const int* __restrict__ perm, const float* __restrict__ gatew,
    float* __restrict__ out) {
  __shared__ f16 aT[128 * 32];
  __shared__ f16 bT[128 * 32];
  int e = blockIdx.z;
  int off = offsets[e];
  int cnt = offsets[e + 1] - off;
  int mt = blockIdx.y;
  if (mt * 128 >= cnt) return;
  int n0 = blockIdx.x * 128;
  int tid = threadIdx.x, lane = tid & 63, wid = tid >> 6;
  const f16* gaBase = hbuf + (size_t)(off + mt * 128) * H_HID;
  const f16* gbBase = wdt + (size_t)e * D_IN * H_HID;

  f32x4 acc[4][4] = {};

  for (int kt = 0; kt < H_HID / 32; ++kt) {
    __syncthreads();
#pragma unroll
    for (int i = 0; i < 2; ++i) {
      int linear = i * 256 + tid;
      int row = linear >> 2, chunk = linear & 3;
      gload_lds16(gaBase + (size_t)row * H_HID + chunk * 8 + kt * 32,
                  &aT[(i * 256 + wid * 64) * 8]);
      gload_lds16(gbBase + (size_t)(n0 + row) * H_HID + chunk * 8 + kt * 32,
                  &bT[(i * 256 + wid * 64) * 8]);
    }
    __syncthreads();
    f16x8 af[4], bf[4];
    int krow = (lane >> 4) * 8;
    int wm = (wid >> 1) * 64, wn = (wid & 1) * 64;
#pragma unroll
    for (int m = 0; m < 4; ++m)
      af[m] = *(const f16x8*)&aT[(wm + m * 16 + (lane & 15)) * 32 + krow];
#pragma unroll
    for (int n = 0; n < 4; ++n)
      bf[n] = *(const f16x8*)&bT[(wn + n * 16 + (lane & 15)) * 32 + krow];
#pragma unroll
    for (int m = 0; m < 4; ++m)
#pragma unroll
      for (int n = 0; n < 4; ++n)
        acc[m][n] = __builtin_amdgcn_mfma_f32_16x16x32_f16(af[m], bf[n], acc[m][n], 0, 0, 0);
  }

  int wm = (wid >> 1) * 64, wn = (wid & 1) * 64;
#pragma unroll
  for (int n = 0; n < 4; ++n) {
    int col = n0 + wn + n * 16 + (lane & 15);
    float bdv = bd[e * D_IN + col];
#pragma unroll
    for (int m = 0; m < 4; ++m) {
#pragma unroll
      for (int r = 0; r < 4; ++r) {
        int row = wm + m * 16 + (lane >> 4) * 4 + r;
        int local = mt * 128 + row;
        if (local < cnt) {
          int slot = off + local;
          int token = perm[slot];
          float g = gatew[slot];
          atomicAdd(&out[(size_t)token * D_IN + col], g * (acc[m][n][r] + bdv));
        }
      }
    }
  }
}

// ---------------- launch ----------------

extern "C" void kernel_launch(void* const* d_in, const int* in_sizes, int n_in,
                              void* d_out, int out_size, void* d_ws, size_t ws_size,
                              hipStream_t stream) {
  const float* x  = (const float*)d_in[0];
  const float* Wr = (const float*)d_in[1];
  const float* br = (const float*)d_in[2];
  const float* Wg = (const float*)d_in[3];
  const float* bg = (const float*)d_in[4];
  const float* Wu = (const float*)d_in[5];
  const float* bu = (const float*)d_in[6];
  const float* Wd = (const float*)d_in[7];
  const float* bd = (const float*)d_in[8];
  float* out = (float*)d_out;

  char* ws = (char*)d_ws;
  size_t o = 0;
  auto alloc = [&](size_t bytes) {
    size_t r = o;
    o += (bytes + 255) & ~(size_t)255;
    return r;
  };
  f16* xb     = (f16*)(ws + alloc((size_t)T_TOK * D_IN * 2));
  f16* wgt    = (f16*)(ws + alloc((size_t)E_EXP * H_HID * D_IN * 2));
  f16* wut    = (f16*)(ws + alloc((size_t)E_EXP * H_HID * D_IN * 2));
  f16* wdt    = (f16*)(ws + alloc((size_t)E_EXP * D_IN * H_HID * 2));
  f16* hbuf   = (f16*)(ws + alloc((size_t)NSLOT_PAD * H_HID * 2));
  int* eidx   = (int*)(ws + alloc((size_t)T_TOK * 4));
  float2* pval= (float2*)(ws + alloc((size_t)T_TOK * 8));
  int* counts = (int*)(ws + alloc(64 * 4));  // counts[8] | cursors[8] | offsets[9]
  int* cursors = counts + 8;
  int* offsets = counts + 16;
  int* perm   = (int*)(ws + alloc((size_t)NSLOT_PAD * 4));
  float* gatew= (float*)(ws + alloc((size_t)NSLOT_PAD * 4));

  hipMemsetAsync(d_out, 0, (size_t)out_size * sizeof(float), stream);
  hipMemsetAsync(counts, 0, 64 * 4, stream);

  convert_x_kernel<<<(T_TOK * D_IN / 4 + 255) / 256, 256, 0, stream>>>(
      x, xb, T_TOK * D_IN / 4);
  transpose_cvt_kernel<<<dim3(H_HID / 32, D_IN / 32, E_EXP), 256, 0, stream>>>(
      Wg, wgt, D_IN, H_HID);
  transpose_cvt_kernel<<<dim3(H_HID / 32, D_IN / 32, E_EXP), 256, 0, stream>>>(
      Wu, wut, D_IN, H_HID);
  transpose_cvt_kernel<<<dim3(D_IN / 32, H_HID / 32, E_EXP), 256, 0, stream>>>(
      Wd, wdt, H_HID, D_IN);
  router_kernel<<<T_TOK / 4, 256, 0, stream>>>(x, Wr, br, eidx, pval, counts);
  scan_kernel<<<1, 64, 0, stream>>>(counts, offsets);
  scatter_kernel<<<T_TOK / 256, 256, 0, stream>>>(eidx, pval, offsets, cursors, perm, gatew);
  ffn1_kernel<<<dim3(H_HID / 64, 64, E_EXP), 256, 0, stream>>>(
      xb, wgt, wut, bg, bu, offsets, perm, hbuf);
  ffn2_kernel<<<dim3(D_IN / 128, 64, E_EXP), 256, 0, stream>>>(
      hbuf, wdt, bd, offsets, perm, gatew, out);
}

// Round 2
// 1074.805 us; speedup vs baseline: 1.0565x; 1.0565x over previous
//
#include <hip/hip_runtime.h>
#include <hip/hip_fp16.h>

// MoE: B=4 S=2048 D=1024 E=8 K=2 H=4096. T=8192 tokens, 16384 assignments.
// Sparse grouped-GEMM MoE, fp16 MFMA (fp32 accum).
// R2: XOR-swizzled LDS (conflict-free ds_read_b128), BK=64, FFN1 128x128
// dual-acc tile, FFN2 epilogue -> ybuf f16 + combine (no atomics).

#define T_TOK 8192
#define D_IN  1024
#define E_EXP 8
#define H_HID 4096
#define NSLOT (T_TOK * 2)
#define NSLOT_PAD (NSLOT + 128)

typedef _Float16 f16;
typedef __attribute__((ext_vector_type(8))) _Float16 f16x8;
typedef __attribute__((ext_vector_type(4))) _Float16 f16x4;
typedef __attribute__((ext_vector_type(4))) float f32x4;

__device__ __forceinline__ void gload_lds16(const void* g, void* l) {
  __builtin_amdgcn_global_load_lds(
      (const __attribute__((address_space(1))) unsigned int*)g,
      (__attribute__((address_space(3))) unsigned int*)l, 16, 0, 0);
}

// ---------------- conversion kernels ----------------

__global__ __launch_bounds__(256) void convert_x_kernel(
    const float* __restrict__ x, f16* __restrict__ xb, int n4) {
  int i = blockIdx.x * 256 + threadIdx.x;
  if (i >= n4) return;
  float4 v = ((const float4*)x)[i];
  f16x4 o = {(f16)v.x, (f16)v.y, (f16)v.z, (f16)v.w};
  *(f16x4*)(xb + (size_t)i * 4) = o;
}

// src [batch][R][C] f32  ->  dst [batch][C][R] f16
__global__ __launch_bounds__(256) void transpose_cvt_kernel(
    const float* __restrict__ src, f16* __restrict__ dst, int R, int C) {
  __shared__ float tile[32][33];
  int b = blockIdx.z;
  const float* s = src + (size_t)b * R * C;
  f16* d = dst + (size_t)b * R * C;
  int c0 = blockIdx.x * 32, r0 = blockIdx.y * 32;
  int tr = threadIdx.x >> 3;
  int tc4 = (threadIdx.x & 7) * 4;
  float4 v = *(const float4*)(s + (size_t)(r0 + tr) * C + c0 + tc4);
  tile[tr][tc4 + 0] = v.x;
  tile[tr][tc4 + 1] = v.y;
  tile[tr][tc4 + 2] = v.z;
  tile[tr][tc4 + 3] = v.w;
  __syncthreads();
  f16x4 o = {(f16)tile[tc4 + 0][tr], (f16)tile[tc4 + 1][tr],
             (f16)tile[tc4 + 2][tr], (f16)tile[tc4 + 3][tr]};
  *(f16x4*)(d + (size_t)(c0 + tr) * R + r0 + tc4) = o;
}

// ---------------- router ----------------

__global__ __launch_bounds__(256) void router_kernel(
    const float* __restrict__ x, const float* __restrict__ Wr,
    const float* __restrict__ br, int* __restrict__ eidx,
    float2* __restrict__ pval, int* __restrict__ counts) {
  int lane = threadIdx.x & 63, wid = threadIdx.x >> 6;
  int t = blockIdx.x * 4 + wid;
  const float* xr = x + (size_t)t * D_IN;
  float s[8] = {0.f, 0.f, 0.f, 0.f, 0.f, 0.f, 0.f, 0.f};
  int dbase = lane * 16;
#pragma unroll
  for (int i = 0; i < 4; ++i) {
    float4 xv = *(const float4*)(xr + dbase + i * 4);
    const float xs[4] = {xv.x, xv.y, xv.z, xv.w};
#pragma unroll
    for (int j = 0; j < 4; ++j) {
      const float* wr = Wr + (size_t)(dbase + i * 4 + j) * E_EXP;
      float4 w0 = *(const float4*)wr;
      float4 w1 = *(const float4*)(wr + 4);
      float xvj = xs[j];
      s[0] += xvj * w0.x; s[1] += xvj * w0.y; s[2] += xvj * w0.z; s[3] += xvj * w0.w;
      s[4] += xvj * w1.x; s[5] += xvj * w1.y; s[6] += xvj * w1.z; s[7] += xvj * w1.w;
    }
  }
#pragma unroll
  for (int off = 32; off; off >>= 1)
#pragma unroll
    for (int e = 0; e < 8; ++e) s[e] += __shfl_xor(s[e], off);
  if (lane == 0) {
    float v[8];
#pragma unroll
    for (int e = 0; e < 8; ++e) v[e] = s[e] + br[e];
    int i0 = 0; float v0 = v[0];
#pragma unroll
    for (int e = 1; e < 8; ++e) if (v[e] > v0) { v0 = v[e]; i0 = e; }
    int i1 = -1; float v1 = -1e30f;
#pragma unroll
    for (int e = 0; e < 8; ++e)
      if (e != i0 && v[e] > v1) { v1 = v[e]; i1 = e; }
    float ed = __expf(v1 - v0);
    float inv = 1.f / (1.f + ed);
    eidx[t] = i0 | (i1 << 8);
    pval[t] = make_float2(inv, ed * inv);
    atomicAdd(&counts[i0], 1);
    atomicAdd(&counts[i1], 1);
  }
}

__global__ void scan_kernel(const int* __restrict__ counts, int* __restrict__ offsets) {
  if (threadIdx.x == 0) {
    int acc = 0;
#pragma unroll
    for (int e = 0; e < E_EXP; ++e) { offsets[e] = acc; acc += counts[e]; }
    offsets[E_EXP] = acc;
  }
}

__global__ __launch_bounds__(256) void scatter_kernel(
    const int* __restrict__ eidx, const float2* __restrict__ pval,
    const int* __restrict__ offsets, int* __restrict__ cursors,
    int* __restrict__ perm, float* __restrict__ gatew, int2* __restrict__ slotAB) {
  int t = blockIdx.x * 256 + threadIdx.x;
  if (t >= T_TOK) return;
  int ei = eidx[t];
  float2 p = pval[t];
  int e0 = ei & 0xff, e1 = (ei >> 8) & 0xff;
  int s0 = offsets[e0] + atomicAdd(&cursors[e0], 1);
  perm[s0] = t; gatew[s0] = p.x;
  int s1 = offsets[e1] + atomicAdd(&cursors[e1], 1);
  perm[s1] = t; gatew[s1] = p.y;
  slotAB[t] = make_int2(s0, s1);
}

// ---------------- FFN1: h = silu(X Wg + bg) * (X Wu + bu) ----------------
// 128 slots x 128 h-cols, BK=64, 4 waves 2x2 (each 64x64 of both g and u).
// LDS layout [row][64] f16; 16B chunk c of row r stored at physical c^(r&7).
__global__ __launch_bounds__(256, 2) void ffn1_kernel(
    const f16* __restrict__ xb, const f16* __restrict__ wgt,
    const f16* __restrict__ wut, const float* __restrict__ bg,
    const float* __restrict__ bu, const int* __restrict__ offsets,
    const int* __restrict__ perm, f16* __restrict__ hbuf) {
  __shared__ f16 aT[128 * 64];
  __shared__ f16 bgT[128 * 64];
  __shared__ f16 buT[128 * 64];
  int e = blockIdx.z;
  int off = offsets[e];
  int cnt = offsets[e + 1] - off;
  int mt = blockIdx.y;
  if (mt * 128 >= cnt) return;
  int n0 = blockIdx.x * 128;
  int tid = threadIdx.x, lane = tid & 63, wid = tid >> 6;
  int wr = wid >> 1, wc = wid & 1;
  int l15 = lane & 15, lc0 = lane >> 4;

  // staging sources: linear chunk L = i*256+tid -> physical (row=L>>3, p=L&7)
  // holds logical chunk p^(row&7)  (inverse-swizzled source, linear dest)
  const f16 *gA[4], *gG[4], *gU[4];
#pragma unroll
  for (int i = 0; i < 4; ++i) {
    int linear = i * 256 + tid;
    int row = linear >> 3, p = linear & 7;
    int lc = p ^ (row & 7);
    int srow = min(off + mt * 128 + row, off + cnt - 1);
    gA[i] = xb + (size_t)perm[srow] * D_IN + lc * 8;
    gG[i] = wgt + (size_t)e * H_HID * D_IN + (size_t)(n0 + row) * D_IN + lc * 8;
    gU[i] = wut + (size_t)e * H_HID * D_IN + (size_t)(n0 + row) * D_IN + lc * 8;
  }

  f32x4 accg[4][4] = {};
  f32x4 accu[4][4] = {};

  for (int kt = 0; kt < D_IN / 64; ++kt) {
    __syncthreads();
#pragma unroll
    for (int i = 0; i < 4; ++i) {
      gload_lds16(gA[i] + kt * 64, &aT[(i * 256 + wid * 64) * 8]);
      gload_lds16(gG[i] + kt * 64, &bgT[(i * 256 + wid * 64) * 8]);
      gload_lds16(gU[i] + kt * 64, &buT[(i * 256 + wid * 64) * 8]);
    }
    __syncthreads();
#pragma unroll
    for (int kk = 0; kk < 2; ++kk) {
      int c = kk * 4 + lc0;
      f16x8 af[4];
#pragma unroll
      for (int m = 0; m < 4; ++m) {
        int r = wr * 64 + m * 16 + l15;
        af[m] = *(const f16x8*)&aT[r * 64 + (c ^ (r & 7)) * 8];
      }
#pragma unroll
      for (int n = 0; n < 4; ++n) {
        int r = wc * 64 + n * 16 + l15;
        int o8 = r * 64 + (c ^ (r & 7)) * 8;
        f16x8 bgf = *(const f16x8*)&bgT[o8];
#pragma unroll
        for (int m = 0; m < 4; ++m)
          accg[m][n] = __builtin_amdgcn_mfma_f32_16x16x32_f16(af[m], bgf, accg[m][n], 0, 0, 0);
        f16x8 buf_ = *(const f16x8*)&buT[o8];
#pragma unroll
        for (int m = 0; m < 4; ++m)
          accu[m][n] = __builtin_amdgcn_mfma_f32_16x16x32_f16(af[m], buf_, accu[m][n], 0, 0, 0);
      }
    }
  }

#pragma unroll
  for (int n = 0; n < 4; ++n) {
    int h = n0 + wc * 64 + n * 16 + l15;
    float bgv = bg[e * H_HID + h];
    float buv = bu[e * H_HID + h];
#pragma unroll
    for (int m = 0; m < 4; ++m) {
#pragma unroll
      for (int r = 0; r < 4; ++r) {
        int local = mt * 128 + wr * 64 + m * 16 + lc0 * 4 + r;
        if (local < cnt) {
          float g = accg[m][n][r] + bgv;
          float u = accu[m][n][r] + buv;
          hbuf[(size_t)(off + local) * H_HID + h] = (f16)((g / (1.f + __expf(-g))) * u);
        }
      }
    }
  }
}

// ---------------- FFN2: ybuf[slot] = gate * (h Wd + bd)  (f16) ----------------
// 128 slots x 128 d-cols, BK=64, 4 waves 2x2, same swizzled LDS.
__global__ __launch_bounds__(256, 2) void ffn2_kernel(
    const f16* __restrict__ hbuf, const f16* __restrict__ wdt,
    const float* __restrict__ bd, const int* __restrict__ offsets,
    const float* __restrict__ gatew, f16* __restrict__ ybuf) {
  __shared__ f16 aT[128 * 64];
  __shared__ f16 bT[128 * 64];
  int e = blockIdx.z;
  int off = offsets[e];
  int cnt = offsets[e + 1] - off;
  int mt = blockIdx.y;
  if (mt * 128 >= cnt) return;
  int n0 = blockIdx.x * 128;
  int tid = threadIdx.x, lane = tid & 63, wid = tid >> 6;
  int wr = wid >> 1, wc = wid & 1;
  int l15 = lane & 15, lc0 = lane >> 4;
  const f16* gaBase = hbuf + (size_t)(off + mt * 128) * H_HID;
  const f16* gbBase = wdt + (size_t)e * D_IN * H_HID;

  const f16 *gA[4], *gB[4];
#pragma unroll
  for (int i = 0; i < 4; ++i) {
    int linear = i * 256 + tid;
    int row = linear >> 3, p = linear & 7;
    int lc = p ^ (row & 7);
    gA[i] = gaBase + (size_t)row * H_HID + lc * 8;
    gB[i] = gbBase + (size_t)(n0 + row) * H_HID + lc * 8;
  }

  f32x4 acc[4][4] = {};

  for (int kt = 0; kt < H_HID / 64; ++kt) {
    __syncthreads();
#pragma unroll
    for (int i = 0; i < 4; ++i) {
      gload_lds16(gA[i] + kt * 64, &aT[(i * 256 + wid * 64) * 8]);
      gload_lds16(gB[i] + kt * 64, &bT[(i * 256 + wid * 64) * 8]);
    }
    __syncthreads();
#pragma unroll
    for (int kk = 0; kk < 2; ++kk) {
      int c = kk * 4 + lc0;
      f16x8 af[4];
#pragma unroll
      for (int m = 0; m < 4; ++m) {
        int r = wr * 64 + m * 16 + l15;
        af[m] = *(const f16x8*)&aT[r * 64 + (c ^ (r & 7)) * 8];
      }
#pragma unroll
      for (int n = 0; n < 4; ++n) {
        int r = wc * 64 + n * 16 + l15;
        f16x8 bf = *(const f16x8*)&bT[r * 64 + (c ^ (r & 7)) * 8];
#pragma unroll
        for (int m = 0; m < 4; ++m)
          acc[m][n] = __builtin_amdgcn_mfma_f32_16x16x32_f16(af[m], bf, acc[m][n], 0, 0, 0);
      }
    }
  }

#pragma unroll
  for (int n = 0; n < 4; ++n) {
    int col = n0 + wc * 64 + n * 16 + l15;
    float bdv = bd[e * D_IN + col];
#pragma unroll
    for (int m = 0; m < 4; ++m) {
#pragma unroll
      for (int r = 0; r < 4; ++r) {
        int local = mt * 128 + wr * 64 + m * 16 + lc0 * 4 + r;
        if (local < cnt) {
          int slot = off + local;
          ybuf[(size_t)slot * D_IN + col] = (f16)(gatew[slot] * (acc[m][n][r] + bdv));
        }
      }
    }
  }
}

// ---------------- combine: out[t] = ybuf[s0] + ybuf[s1] ----------------
__global__ __launch_bounds__(256) void combine_kernel(
    const f16* __restrict__ ybuf, const int2* __restrict__ slotAB,
    float* __restrict__ out) {
  int i = blockIdx.x * 256 + threadIdx.x;  // T*D/8 threads
  int t = i >> 7;                          // D/8 = 128 chunks per token
  int c8 = i & 127;
  int2 s = slotAB[t];
  f16x8 y0 = *(const f16x8*)(ybuf + (size_t)s.x * D_IN + c8 * 8);
  f16x8 y1 = *(const f16x8*)(ybuf + (size_t)s.y * D_IN + c8 * 8);
  float* o = out + (size_t)t * D_IN + c8 * 8;
  float4 o0 = make_float4((float)y0[0] + (float)y1[0], (float)y0[1] + (float)y1[1],
                          (float)y0[2] + (float)y1[2], (float)y0[3] + (float)y1[3]);
  float4 o1 = make_float4((float)y0[4] + (float)y1[4], (float)y0[5] + (float)y1[5],
                          (float)y0[6] + (float)y1[6], (float)y0[7] + (float)y1[7]);
  ((float4*)o)[0] = o0;
  ((float4*)o)[1] = o1;
}

// ---------------- launch ----------------

extern "C" void kernel_launch(void* const* d_in, const int* in_sizes, int n_in,
                              void* d_out, int out_size, void* d_ws, size_t ws_size,
                              hipStream_t stream) {
  const float* x  = (const float*)d_in[0];
  const float* Wr = (const float*)d_in[1];
  const float* br = (const float*)d_in[2];
  const float* Wg = (const float*)d_in[3];
  const float* bg = (const float*)d_in[4];
  const float* Wu = (const float*)d_in[5];
  const float* bu = (const float*)d_in[6];
  const float* Wd = (const float*)d_in[7];
  const float* bd = (const float*)d_in[8];
  float* out = (float*)d_out;

  char* ws = (char*)d_ws;
  size_t o = 0;
  auto alloc = [&](size_t bytes) {
    size_t r = o;
    o += (bytes + 255) & ~(size_t)255;
    return r;
  };
  f16* xb     = (f16*)(ws + alloc((size_t)T_TOK * D_IN * 2));
  f16* wgt    = (f16*)(ws + alloc((size_t)E_EXP * H_HID * D_IN * 2));  // 64MB
  f16* wut    = (f16*)(ws + alloc((size_t)E_EXP * H_HID * D_IN * 2));
  f16* wdt    = (f16*)(ws + alloc((size_t)E_EXP * D_IN * H_HID * 2));
  f16* hbuf   = (f16*)(ws + alloc((size_t)NSLOT_PAD * H_HID * 2));
  int* eidx   = (int*)(ws + alloc((size_t)T_TOK * 4));
  float2* pval= (float2*)(ws + alloc((size_t)T_TOK * 8));
  int* counts = (int*)(ws + alloc(64 * 4));  // counts[8] | cursors[8] | offsets[9]
  int* cursors = counts + 8;
  int* offsets = counts + 16;
  int* perm   = (int*)(ws + alloc((size_t)NSLOT_PAD * 4));
  float* gatew= (float*)(ws + alloc((size_t)NSLOT_PAD * 4));
  int2* slotAB= (int2*)(ws + alloc((size_t)T_TOK * 8));
  // ybuf aliases wgt: wgt is dead after ffn1, ybuf written by ffn2 (after).
  f16* ybuf   = wgt;  // needs NSLOT_PAD*D_IN*2 = 33.8MB <= 64MB

  hipMemsetAsync(counts, 0, 64 * 4, stream);

  convert_x_kernel<<<(T_TOK * D_IN / 4 + 255) / 256, 256, 0, stream>>>(
      x, xb, T_TOK * D_IN / 4);
  transpose_cvt_kernel<<<dim3(H_HID / 32, D_IN / 32, E_EXP), 256, 0, stream>>>(
      Wg, wgt, D_IN, H_HID);
  transpose_cvt_kernel<<<dim3(H_HID / 32, D_IN / 32, E_EXP), 256, 0, stream>>>(
      Wu, wut, D_IN, H_HID);
  transpose_cvt_kernel<<<dim3(D_IN / 32, H_HID / 32, E_EXP), 256, 0, stream>>>(
      Wd, wdt, H_HID, D_IN);
  router_kernel<<<T_TOK / 4, 256, 0, stream>>>(x, Wr, br, eidx, pval, counts);
  scan_kernel<<<1, 64, 0, stream>>>(counts, offsets);
  scatter_kernel<<<T_TOK / 256, 256, 0, stream>>>(eidx, pval, offsets, cursors,
                                                  perm, gatew, slotAB);
  ffn1_kernel<<<dim3(H_HID / 128, 128, E_EXP), 256, 0, stream>>>(
      xb, wgt, wut, bg, bu, offsets, perm, hbuf);
  ffn2_kernel<<<dim3(D_IN / 128, 128, E_EXP), 256, 0, stream>>>(
      hbuf, wdt, bd, offsets, gatew, ybuf);
  combine_kernel<<<T_TOK * D_IN / 8 / 256, 256, 0, stream>>>(ybuf, slotAB, out);
}

// Round 3
// 1054.085 us; speedup vs baseline: 1.0773x; 1.0197x over previous
//
#include <hip/hip_runtime.h>
#include <hip/hip_fp16.h>

// MoE: B=4 S=2048 D=1024 E=8 K=2 H=4096. T=8192 tokens, 16384 assignments.
// R3: 256x256/BK=64 8-phase pipelined grouped GEMMs (T2+T3+T4+T5),
// FFN1 gate/up interleaved into one B matrix (16-col groups).

#define T_TOK 8192
#define D_IN  1024
#define E_EXP 8
#define H_HID 4096
#define NSLOT (T_TOK * 2)
#define NSLOT_PAD (NSLOT + 256)

typedef _Float16 f16;
typedef __attribute__((ext_vector_type(8))) _Float16 f16x8;
typedef __attribute__((ext_vector_type(4))) _Float16 f16x4;
typedef __attribute__((ext_vector_type(4))) float f32x4;

__device__ __forceinline__ void gload_lds16(const void* g, void* l) {
  __builtin_amdgcn_global_load_lds(
      (const __attribute__((address_space(1))) unsigned int*)g,
      (__attribute__((address_space(3))) unsigned int*)l, 16, 0, 0);
}

// ---------------- conversion kernels ----------------

__global__ __launch_bounds__(256) void convert_x_kernel(
    const float* __restrict__ x, f16* __restrict__ xb, int n4) {
  int i = blockIdx.x * 256 + threadIdx.x;
  if (i >= n4) return;
  float4 v = ((const float4*)x)[i];
  f16x4 o = {(f16)v.x, (f16)v.y, (f16)v.z, (f16)v.w};
  *(f16x4*)(xb + (size_t)i * 4) = o;
}

// src [e][R][C] f32 -> dst f16 [e][*][R]; MAP0: row=c; MAP1: gate interleave;
// MAP2: up interleave (rows 32j+16.. for source col 16j..).
template<int MAP>
__global__ __launch_bounds__(256) void transpose_cvt_kernel(
    const float* __restrict__ src, f16* __restrict__ dst, int R, int C,
    size_t dstride) {
  __shared__ float tile[32][33];
  int b = blockIdx.z;
  const float* s = src + (size_t)b * R * C;
  f16* d = dst + (size_t)b * dstride;
  int c0 = blockIdx.x * 32, r0 = blockIdx.y * 32;
  int tr = threadIdx.x >> 3;
  int tc4 = (threadIdx.x & 7) * 4;
  float4 v = *(const float4*)(s + (size_t)(r0 + tr) * C + c0 + tc4);
  tile[tr][tc4 + 0] = v.x;
  tile[tr][tc4 + 1] = v.y;
  tile[tr][tc4 + 2] = v.z;
  tile[tr][tc4 + 3] = v.w;
  __syncthreads();
  int c = c0 + tr;
  int ro = (MAP == 0) ? c : (((c >> 4) << 5) + ((MAP == 2) ? 16 : 0) + (c & 15));
  f16x4 o = {(f16)tile[tc4 + 0][tr], (f16)tile[tc4 + 1][tr],
             (f16)tile[tc4 + 2][tr], (f16)tile[tc4 + 3][tr]};
  *(f16x4*)(d + (size_t)ro * R + r0 + tc4) = o;
}

// ---------------- router ----------------

__global__ __launch_bounds__(256) void router_kernel(
    const float* __restrict__ x, const float* __restrict__ Wr,
    const float* __restrict__ br, int* __restrict__ eidx,
    float2* __restrict__ pval, int* __restrict__ counts) {
  int lane = threadIdx.x & 63, wid = threadIdx.x >> 6;
  int t = blockIdx.x * 4 + wid;
  const float* xr = x + (size_t)t * D_IN;
  float s[8] = {0.f, 0.f, 0.f, 0.f, 0.f, 0.f, 0.f, 0.f};
  int dbase = lane * 16;
#pragma unroll
  for (int i = 0; i < 4; ++i) {
    float4 xv = *(const float4*)(xr + dbase + i * 4);
    const float xs[4] = {xv.x, xv.y, xv.z, xv.w};
#pragma unroll
    for (int j = 0; j < 4; ++j) {
      const float* wr = Wr + (size_t)(dbase + i * 4 + j) * E_EXP;
      float4 w0 = *(const float4*)wr;
      float4 w1 = *(const float4*)(wr + 4);
      float xvj = xs[j];
      s[0] += xvj * w0.x; s[1] += xvj * w0.y; s[2] += xvj * w0.z; s[3] += xvj * w0.w;
      s[4] += xvj * w1.x; s[5] += xvj * w1.y; s[6] += xvj * w1.z; s[7] += xvj * w1.w;
    }
  }
#pragma unroll
  for (int off = 32; off; off >>= 1)
#pragma unroll
    for (int e = 0; e < 8; ++e) s[e] += __shfl_xor(s[e], off);
  if (lane == 0) {
    float v[8];
#pragma unroll
    for (int e = 0; e < 8; ++e) v[e] = s[e] + br[e];
    int i0 = 0; float v0 = v[0];
#pragma unroll
    for (int e = 1; e < 8; ++e) if (v[e] > v0) { v0 = v[e]; i0 = e; }
    int i1 = -1; float v1 = -1e30f;
#pragma unroll
    for (int e = 0; e < 8; ++e)
      if (e != i0 && v[e] > v1) { v1 = v[e]; i1 = e; }
    float ed = __expf(v1 - v0);
    float inv = 1.f / (1.f + ed);
    eidx[t] = i0 | (i1 << 8);
    pval[t] = make_float2(inv, ed * inv);
    atomicAdd(&counts[i0], 1);
    atomicAdd(&counts[i1], 1);
  }
}

__global__ void scan_kernel(const int* __restrict__ counts, int* __restrict__ offsets) {
  if (threadIdx.x == 0) {
    int acc = 0;
#pragma unroll
    for (int e = 0; e < E_EXP; ++e) { offsets[e] = acc; acc += counts[e]; }
    offsets[E_EXP] = acc;
  }
}

__global__ __launch_bounds__(256) void scatter_kernel(
    const int* __restrict__ eidx, const float2* __restrict__ pval,
    const int* __restrict__ offsets, int* __restrict__ cursors,
    int* __restrict__ perm, float* __restrict__ gatew, int2* __restrict__ slotAB) {
  int t = blockIdx.x * 256 + threadIdx.x;
  if (t >= T_TOK) return;
  int ei = eidx[t];
  float2 p = pval[t];
  int e0 = ei & 0xff, e1 = (ei >> 8) & 0xff;
  int s0 = offsets[e0] + atomicAdd(&cursors[e0], 1);
  perm[s0] = t; gatew[s0] = p.x;
  int s1 = offsets[e1] + atomicAdd(&cursors[e1], 1);
  perm[s1] = t; gatew[s1] = p.y;
  slotAB[t] = make_int2(s0, s1);
}

// ---------------- 8-phase 256x256 grouped GEMM ----------------
// 512 thr = 8 waves (2M x 4N). LDS 128KB: buf{0,1} x (A[256][64] | B[256][64]),
// rows 128B, 16B chunk c of row r at physical c^(r&7).
// MODE0 (FFN1): A=xb gathered via perm, B=wgut (gate/up 16-col interleave),
//   K=1024, epilogue silu(g)*u -> hbuf. MODE1 (FFN2): A=hbuf, B=wdt, K=4096,
//   epilogue gate*(acc+bd) -> ybuf.

#define SB0 __builtin_amdgcn_sched_barrier(0)
#define BAR do { SB0; __builtin_amdgcn_s_barrier(); SB0; } while (0)

#define STAGE_(B, ISB, H, KT, BASE) do {                                   \
  char* d_ = smem + (B)*65536 + (ISB)*32768 + (H)*16384 + wid*1024;        \
  gload_lds16(BASE[(H)*2+0] + (size_t)(KT)*64, d_);                        \
  gload_lds16(BASE[(H)*2+1] + (size_t)(KT)*64, d_ + 8192);                 \
} while (0)

#define LDA_(B, Q)                                                          \
  _Pragma("unroll")                                                         \
  for (int m_ = 0; m_ < 4; ++m_) {                                          \
    fa[m_][0] = *(const f16x8*)(smem + (B)*65536 + aoff + ((Q)*4+m_)*2048 + offk0); \
    fa[m_][1] = *(const f16x8*)(smem + (B)*65536 + aoff + ((Q)*4+m_)*2048 + offk1); \
  }

#define LDB_(FB, B, RH)                                                     \
  _Pragma("unroll")                                                         \
  for (int n_ = 0; n_ < 2; ++n_) {                                          \
    FB[n_][0] = *(const f16x8*)(smem + (B)*65536 + 32768 + boff + ((RH)*2+n_)*2048 + offk0); \
    FB[n_][1] = *(const f16x8*)(smem + (B)*65536 + 32768 + boff + ((RH)*2+n_)*2048 + offk1); \
  }

#define QUAD_(Q, RH, FB)                                                    \
  __builtin_amdgcn_s_setprio(1);                                            \
  _Pragma("unroll")                                                         \
  for (int m_ = 0; m_ < 4; ++m_)                                            \
    _Pragma("unroll")                                                       \
    for (int n_ = 0; n_ < 2; ++n_) {                                        \
      acc[(Q)*4+m_][(RH)*2+n_] = __builtin_amdgcn_mfma_f32_16x16x32_f16(    \
          fa[m_][0], FB[n_][0], acc[(Q)*4+m_][(RH)*2+n_], 0, 0, 0);         \
      acc[(Q)*4+m_][(RH)*2+n_] = __builtin_amdgcn_mfma_f32_16x16x32_f16(    \
          fa[m_][1], FB[n_][1], acc[(Q)*4+m_][(RH)*2+n_], 0, 0, 0);         \
    }                                                                       \
  __builtin_amdgcn_s_setprio(0);

template<int MODE>
__global__ __launch_bounds__(512, 2) void ffn_8ph_kernel(
    const f16* __restrict__ Asrc, const f16* __restrict__ Bsrc,
    const float* __restrict__ bias0, const float* __restrict__ bias1,
    const int* __restrict__ offsets, const int* __restrict__ perm,
    const float* __restrict__ gatew, f16* __restrict__ dst) {
  constexpr int KD = MODE ? H_HID : D_IN;        // K dim
  constexpr int BROWS = MODE ? D_IN : 2 * H_HID; // B rows per expert
  constexpr int NT = KD / 64;                    // K-tiles (even)
  static_assert(NT % 2 == 0, "NT even");

  __shared__ __align__(16) char smem[131072];

  int nt = blockIdx.x, e = blockIdx.y, mt = blockIdx.z;
  int off = offsets[e];
  int cnt = offsets[e + 1] - off;
  if (mt * 256 >= cnt) return;

  int tid = threadIdx.x, lane = tid & 63, wid = tid >> 6;
  int wm = wid >> 2, wn = wid & 3;
  int l15 = lane & 15, lc0 = lane >> 4, s7 = l15 & 7;
  int aoff = (wm * 128 + l15) * 128;
  int boff = (wn * 64 + l15) * 128;
  int offk0 = ((lc0) ^ s7) * 16;
  int offk1 = ((lc0 + 4) ^ s7) * 16;

  // stage source pointers: [half*2 + issue]
  const f16 *aB[4], *bB[4];
#pragma unroll
  for (int h = 0; h < 2; ++h)
#pragma unroll
    for (int i = 0; i < 2; ++i) {
      int chunk = (i * 8 + wid) * 64 + lane;
      int rowh = chunk >> 3;
      int lc = (chunk & 7) ^ (rowh & 7);
      int absrow = h * 128 + rowh;
      int slot = off + min(mt * 256 + absrow, cnt - 1);
      if constexpr (MODE == 0)
        aB[h * 2 + i] = Asrc + (size_t)perm[slot] * KD + lc * 8;
      else
        aB[h * 2 + i] = Asrc + (size_t)slot * KD + lc * 8;
      bB[h * 2 + i] = Bsrc + ((size_t)e * BROWS + nt * 256 + absrow) * KD + lc * 8;
    }

  f32x4 acc[8][4] = {};
  f16x8 fa[4][2], fb01[2][2], fb23[2][2];

  // prologue: buf0 <- tile0 (B,A), buf1.B <- tile1
  STAGE_(0, 1, 0, 0, bB); STAGE_(0, 1, 1, 0, bB);
  STAGE_(0, 0, 0, 0, aB); STAGE_(0, 0, 1, 0, aB);
  STAGE_(1, 1, 0, 1, bB); STAGE_(1, 1, 1, 1, bB);
  asm volatile("s_waitcnt vmcnt(4)" ::: "memory");
  BAR;

  for (int it = 0; it < NT / 2; ++it) {
    int t1 = 2 * it + 1;
    int t2 = min(2 * it + 2, NT - 1);
    int t3 = min(2 * it + 3, NT - 1);
    // P1: compute t0.quad(0,0) from buf0; stage buf1.A0 (t1)
    LDA_(0, 0); LDB_(fb01, 0, 0); STAGE_(1, 0, 0, t1, aB);
    BAR; QUAD_(0, 0, fb01); BAR;
    // P2
    LDB_(fb23, 0, 1); STAGE_(1, 0, 1, t1, aB);
    BAR; QUAD_(0, 1, fb23); BAR;
    // P3
    LDA_(0, 1); STAGE_(0, 1, 0, t2, bB);
    BAR; QUAD_(1, 0, fb01); BAR;
    // P4
    STAGE_(0, 1, 1, t2, bB);
    asm volatile("s_waitcnt vmcnt(4)" ::: "memory");
    BAR; QUAD_(1, 1, fb23); BAR;
    // P5: compute t1 from buf1; stage buf0.A0 (t2)
    LDA_(1, 0); LDB_(fb01, 1, 0); STAGE_(0, 0, 0, t2, aB);
    BAR; QUAD_(0, 0, fb01); BAR;
    // P6
    LDB_(fb23, 1, 1); STAGE_(0, 0, 1, t2, aB);
    BAR; QUAD_(0, 1, fb23); BAR;
    // P7
    LDA_(1, 1); STAGE_(1, 1, 0, t3, bB);
    BAR; QUAD_(1, 0, fb01); BAR;
    // P8
    STAGE_(1, 1, 1, t3, bB);
    asm volatile("s_waitcnt vmcnt(4)" ::: "memory");
    BAR; QUAD_(1, 1, fb23); BAR;
  }

  asm volatile("s_waitcnt vmcnt(0)" ::: "memory");
  BAR;

  int c0_ = lc0 * 4;
  if constexpr (MODE == 0) {
#pragma unroll
    for (int p = 0; p < 2; ++p) {
      int h = nt * 128 + wn * 32 + p * 16 + l15;
      float bgv = bias0[e * H_HID + h];
      float buv = bias1[e * H_HID + h];
#pragma unroll
      for (int m = 0; m < 8; ++m) {
        int lbase = mt * 256 + wm * 128 + m * 16 + c0_;
#pragma unroll
        for (int r = 0; r < 4; ++r) {
          if (lbase + r < cnt) {
            float g = acc[m][2 * p][r] + bgv;
            float u = acc[m][2 * p + 1][r] + buv;
            dst[(size_t)(off + lbase + r) * H_HID + h] =
                (f16)((g / (1.f + __expf(-g))) * u);
          }
        }
      }
    }
  } else {
#pragma unroll
    for (int n = 0; n < 4; ++n) {
      int col = nt * 256 + wn * 64 + n * 16 + l15;
      float bdv = bias0[e * D_IN + col];
#pragma unroll
      for (int m = 0; m < 8; ++m) {
        int lbase = mt * 256 + wm * 128 + m * 16 + c0_;
#pragma unroll
        for (int r = 0; r < 4; ++r) {
          if (lbase + r < cnt) {
            int slot = off + lbase + r;
            dst[(size_t)slot * D_IN + col] = (f16)(gatew[slot] * (acc[m][n][r] + bdv));
          }
        }
      }
    }
  }
}

// ---------------- combine: out[t] = ybuf[s0] + ybuf[s1] ----------------
__global__ __launch_bounds__(256) void combine_kernel(
    const f16* __restrict__ ybuf, const int2* __restrict__ slotAB,
    float* __restrict__ out) {
  int i = blockIdx.x * 256 + threadIdx.x;
  int t = i >> 7;
  int c8 = i & 127;
  int2 s = slotAB[t];
  f16x8 y0 = *(const f16x8*)(ybuf + (size_t)s.x * D_IN + c8 * 8);
  f16x8 y1 = *(const f16x8*)(ybuf + (size_t)s.y * D_IN + c8 * 8);
  float* o = out + (size_t)t * D_IN + c8 * 8;
  float4 o0 = make_float4((float)y0[0] + (float)y1[0], (float)y0[1] + (float)y1[1],
                          (float)y0[2] + (float)y1[2], (float)y0[3] + (float)y1[3]);
  float4 o1 = make_float4((float)y0[4] + (float)y1[4], (float)y0[5] + (float)y1[5],
                          (float)y0[6] + (float)y1[6], (float)y0[7] + (float)y1[7]);
  ((float4*)o)[0] = o0;
  ((float4*)o)[1] = o1;
}

// ---------------- launch ----------------

extern "C" void kernel_launch(void* const* d_in, const int* in_sizes, int n_in,
                              void* d_out, int out_size, void* d_ws, size_t ws_size,
                              hipStream_t stream) {
  const float* x  = (const float*)d_in[0];
  const float* Wr = (const float*)d_in[1];
  const float* br = (const float*)d_in[2];
  const float* Wg = (const float*)d_in[3];
  const float* bg = (const float*)d_in[4];
  const float* Wu = (const float*)d_in[5];
  const float* bu = (const float*)d_in[6];
  const float* Wd = (const float*)d_in[7];
  const float* bd = (const float*)d_in[8];
  float* out = (float*)d_out;

  char* ws = (char*)d_ws;
  size_t o = 0;
  auto alloc = [&](size_t bytes) {
    size_t r = o;
    o += (bytes + 255) & ~(size_t)255;
    return r;
  };
  f16* xb     = (f16*)(ws + alloc((size_t)T_TOK * D_IN * 2));
  f16* wgut   = (f16*)(ws + alloc((size_t)E_EXP * 2 * H_HID * D_IN * 2)); // 128MB
  f16* wdt    = (f16*)(ws + alloc((size_t)E_EXP * D_IN * H_HID * 2));     // 64MB
  f16* hbuf   = (f16*)(ws + alloc((size_t)NSLOT_PAD * H_HID * 2));        // 135MB
  int* eidx   = (int*)(ws + alloc((size_t)T_TOK * 4));
  float2* pval= (float2*)(ws + alloc((size_t)T_TOK * 8));
  int* counts = (int*)(ws + alloc(64 * 4));
  int* cursors = counts + 8;
  int* offsets = counts + 16;
  int* perm   = (int*)(ws + alloc((size_t)NSLOT_PAD * 4));
  float* gatew= (float*)(ws + alloc((size_t)NSLOT_PAD * 4));
  int2* slotAB= (int2*)(ws + alloc((size_t)T_TOK * 8));
  f16* ybuf   = wgut;  // wgut dead after ffn1; ybuf needs 34MB <= 128MB

  hipMemsetAsync(counts, 0, 64 * 4, stream);

  convert_x_kernel<<<(T_TOK * D_IN / 4 + 255) / 256, 256, 0, stream>>>(
      x, xb, T_TOK * D_IN / 4);
  transpose_cvt_kernel<1><<<dim3(H_HID / 32, D_IN / 32, E_EXP), 256, 0, stream>>>(
      Wg, wgut, D_IN, H_HID, (size_t)2 * H_HID * D_IN);
  transpose_cvt_kernel<2><<<dim3(H_HID / 32, D_IN / 32, E_EXP), 256, 0, stream>>>(
      Wu, wgut, D_IN, H_HID, (size_t)2 * H_HID * D_IN);
  transpose_cvt_kernel<0><<<dim3(D_IN / 32, H_HID / 32, E_EXP), 256, 0, stream>>>(
      Wd, wdt, H_HID, D_IN, (size_t)D_IN * H_HID);
  router_kernel<<<T_TOK / 4, 256, 0, stream>>>(x, Wr, br, eidx, pval, counts);
  scan_kernel<<<1, 64, 0, stream>>>(counts, offsets);
  scatter_kernel<<<T_TOK / 256, 256, 0, stream>>>(eidx, pval, offsets, cursors,
                                                  perm, gatew, slotAB);
  // grid: x=nt (fast), y=e, z=mt (slow) so active blocks are dispatch-contiguous
  ffn_8ph_kernel<0><<<dim3(2 * H_HID / 256, E_EXP, 32), 512, 0, stream>>>(
      xb, wgut, bg, bu, offsets, perm, nullptr, hbuf);
  ffn_8ph_kernel<1><<<dim3(D_IN / 256, E_EXP, 32), 512, 0, stream>>>(
      hbuf, wdt, bd, nullptr, offsets, nullptr, gatew, ybuf);
  combine_kernel<<<T_TOK * D_IN / 8 / 256, 256, 0, stream>>>(ybuf, slotAB, out);
}